// Round 16
// baseline (85.136 us; speedup 1.0000x reference)
//
#include <hip/hip_runtime.h>
#include <hip/hip_bf16.h>

#define BATCH 1024
#define INPUT_DIM 1024
#define NBK 32
#define KDIM 16

typedef __attribute__((ext_vector_type(8))) short short8;
typedef __attribute__((ext_vector_type(4))) float f32x4;

// u8 quantization of act: u = round(act*QS8) + 128, clamped. Bias cancels in
// |a-c|; v_sad_u8 accumulates integer L1 4 bytes/instr;
// exp(-L1/QS8) = exp2(L1_int * (-log2e/QS8)).
#define QS8 16.0f
#define EXPC8 (-0.090168443f)   // -log2(e)/16

#if __has_builtin(__builtin_amdgcn_sad_u8)
__device__ __forceinline__ unsigned int sadu8(unsigned int a, unsigned int b,
                                              unsigned int acc) {
    return __builtin_amdgcn_sad_u8(a, b, acc);
}
#else
__device__ __forceinline__ unsigned int sadu8(unsigned int a, unsigned int b,
                                              unsigned int acc) {
#pragma unroll
    for (int i = 0; i < 4; ++i) {
        int av = (a >> (8 * i)) & 0xFF, bv = (b >> (8 * i)) & 0xFF;
        int d = av - bv;
        acc += (unsigned int)(d < 0 ? -d : d);
    }
    return acc;
}
#endif

#if __has_builtin(__builtin_amdgcn_exp2f)
__device__ __forceinline__ float fast_exp2(float x) {
    return __builtin_amdgcn_exp2f(x);
}
#else
__device__ __forceinline__ float fast_exp2(float x) { return exp2f(x); }
#endif

// pack two fp32 -> one u32 holding two bf16 (truncation): 1 v_perm_b32.
__device__ __forceinline__ unsigned int pk_bf16_trunc(float lo, float hi) {
    union { float f; unsigned u; } a, b;
    a.f = lo; b.f = hi;
    return __builtin_amdgcn_perm(b.u, a.u, 0x07060302u);
}

// ---------------------------------------------------------------------------
// Kernel 1: act2b[k][b][m] (u8, QS8=16) via bf16 MFMA 16x16x32 — VERBATIM
// from R14/R15 (proven). Direct fp32 reads + v_perm packs; 4 waves split d
// 4-way, LDS cross-wave reduce; u8 quantize epilogue.
// Side job: each block copies a 4 KB slice of x -> out[b][0:1024].
// ---------------------------------------------------------------------------
__global__ __launch_bounds__(256) void gemm_k(const float* __restrict__ x,
                                              const float* __restrict__ W,
                                              unsigned char* __restrict__ act2b,
                                              float* __restrict__ out) {
    __shared__ float lds[1536];
    const int bid  = blockIdx.x;
    const int tid  = threadIdx.x;
    const int k    = bid >> 5;
    const int b0   = (bid & 31) * 32;
    const int lane = tid & 63;
    const int w4   = tid >> 6;                 // 0..3: d-quarter
    const int m16  = lane & 15;
    const int quad = lane >> 4;

    // side job: copy x slice into out (each block: 1024 floats, disjoint)
    {
        const int i = bid * 1024 + tid * 4;
        float4 v = *(const float4*)(x + i);
        const int b = i >> 10;
        const int d = i & 1023;
        *(float4*)(out + b * 1056 + d) = v;
    }

    const float* xa0 = x + (b0 + m16) * INPUT_DIM + w4 * 256 + quad * 8;
    const float* xa1 = xa0 + 16 * INPUT_DIM;
    const float* wb  = W + k * (INPUT_DIM * KDIM) + (w4 * 256 + quad * 8) * KDIM + m16;

    f32x4 acc0 = {0.f, 0.f, 0.f, 0.f};
    f32x4 acc1 = {0.f, 0.f, 0.f, 0.f};

#pragma unroll
    for (int s = 0; s < 8; ++s) {
        const float* pa0 = xa0 + s * 32;
        const float* pa1 = xa1 + s * 32;
        const float* pb  = wb + s * 32 * KDIM;
        float4 a0l = *(const float4*)(pa0);
        float4 a0h = *(const float4*)(pa0 + 4);
        float4 a1l = *(const float4*)(pa1);
        float4 a1h = *(const float4*)(pa1 + 4);
        float b0w = pb[0 * KDIM], b1w = pb[1 * KDIM];
        float b2w = pb[2 * KDIM], b3w = pb[3 * KDIM];
        float b4w = pb[4 * KDIM], b5w = pb[5 * KDIM];
        float b6w = pb[6 * KDIM], b7w = pb[7 * KDIM];
        union { unsigned int u[4]; short8 s8; } A0, A1, BV;
        A0.u[0] = pk_bf16_trunc(a0l.x, a0l.y); A0.u[1] = pk_bf16_trunc(a0l.z, a0l.w);
        A0.u[2] = pk_bf16_trunc(a0h.x, a0h.y); A0.u[3] = pk_bf16_trunc(a0h.z, a0h.w);
        A1.u[0] = pk_bf16_trunc(a1l.x, a1l.y); A1.u[1] = pk_bf16_trunc(a1l.z, a1l.w);
        A1.u[2] = pk_bf16_trunc(a1h.x, a1h.y); A1.u[3] = pk_bf16_trunc(a1h.z, a1h.w);
        BV.u[0] = pk_bf16_trunc(b0w, b1w);     BV.u[1] = pk_bf16_trunc(b2w, b3w);
        BV.u[2] = pk_bf16_trunc(b4w, b5w);     BV.u[3] = pk_bf16_trunc(b6w, b7w);
        acc0 = __builtin_amdgcn_mfma_f32_16x16x32_bf16(A0.s8, BV.s8, acc0, 0, 0, 0);
        acc1 = __builtin_amdgcn_mfma_f32_16x16x32_bf16(A1.s8, BV.s8, acc1, 0, 0, 0);
    }

    if (w4 > 0) {
        float* r = &lds[(w4 - 1) * 512 + lane * 8];
        *(float4*)(r)     = make_float4(acc0[0], acc0[1], acc0[2], acc0[3]);
        *(float4*)(r + 4) = make_float4(acc1[0], acc1[1], acc1[2], acc1[3]);
    }
    __syncthreads();
    if (w4 == 0) {
#pragma unroll
        for (int j = 0; j < 3; ++j) {
            const float* r = &lds[j * 512 + lane * 8];
            float4 p0 = *(const float4*)(r);
            float4 p1 = *(const float4*)(r + 4);
            acc0[0] += p0.x; acc0[1] += p0.y; acc0[2] += p0.z; acc0[3] += p0.w;
            acc1[0] += p1.x; acc1[1] += p1.y; acc1[2] += p1.z; acc1[3] += p1.w;
        }
        const int row0 = b0 + quad * 4;
#pragma unroll
        for (int r = 0; r < 4; ++r) {
            float q0 = fminf(fmaxf(acc0[r] * QS8, -127.f), 127.f);
            float q1 = fminf(fmaxf(acc1[r] * QS8, -127.f), 127.f);
            act2b[(k * BATCH + row0 + r) * KDIM + m16] =
                (unsigned char)(128 + (int)rintf(q0));
            act2b[(k * BATCH + row0 + 16 + r) * KDIM + m16] =
                (unsigned char)(128 + (int)rintf(q1));
        }
    }
}

// ---------------------------------------------------------------------------
// Kernel 2: pairfull v2 — R15 structure (no part buffer, no combine, plain
// scattered stores) + restored LDS amortization: 2 b-rows per thread,
// 16 c-groups of 64. Each ds_read_b128 of a c-row now feeds 2 pairs
// (LDS-pipe per pair halves vs R15; R15 estimate put LDS ~10 us/CU, rival
// of VALU). grid (bt=16, k=32) = 512 blocks x 512 thr = 16 waves/CU
// (occupancy unchanged). Per-wave LDS reads have 2 distinct addresses
// (half-wave cg split) = 2-way alias = free [m136]. red: 16 partials/row
// via 4 KB LDS, then direct store to out.
// ---------------------------------------------------------------------------
__global__ __launch_bounds__(512) void pairfull_k(const unsigned char* __restrict__ act2b,
                                                  float* __restrict__ out) {
    __shared__ unsigned int cs[1024 * 4];   // 16 KB: full k-slice, u8 rows
    __shared__ float red[16 * 64];          // 4 KB: per-row partials
    const int tid = threadIdx.x;
    const int k   = blockIdx.y;
    const int bt  = blockIdx.x;
    const int rs  = tid & 31;               // row slot 0..31
    const int cg  = tid >> 5;               // 0..15: c-sixteenth
    const unsigned char* base = act2b + k * (BATCH * KDIM);

    // stage all 1024 c-rows (16 KB), coalesced: 512 thr x 2 uint4
    ((uint4*)cs)[tid]       = ((const uint4*)base)[tid];
    ((uint4*)cs)[tid + 512] = ((const uint4*)base)[tid + 512];

    // own rows (rs and rs+32), 4 u32 = 16 u8 each
    uint4 ua = *(const uint4*)(base + (bt * 64 + rs) * KDIM);
    uint4 ub = *(const uint4*)(base + (bt * 64 + rs + 32) * KDIM);
    __syncthreads();

    float f0 = 0.f, f1 = 0.f;
    const unsigned int* cbase = cs + cg * 64 * 4;
#pragma unroll 4
    for (int c = 0; c < 64; ++c) {
        uint4 q = *(const uint4*)&cbase[c * 4];
        unsigned int s0 = 0u, s1 = 0u;
        s0 = sadu8(ua.x, q.x, s0); s1 = sadu8(ub.x, q.x, s1);
        s0 = sadu8(ua.y, q.y, s0); s1 = sadu8(ub.y, q.y, s1);
        s0 = sadu8(ua.z, q.z, s0); s1 = sadu8(ub.z, q.z, s1);
        s0 = sadu8(ua.w, q.w, s0); s1 = sadu8(ub.w, q.w, s1);
        f0 += fast_exp2((float)s0 * EXPC8);
        f1 += fast_exp2((float)s1 * EXPC8);
    }

    red[cg * 64 + rs]      = f0;
    red[cg * 64 + rs + 32] = f1;
    __syncthreads();
    if (tid < 64) {
        float s = 0.f;
#pragma unroll
        for (int j = 0; j < 16; ++j) s += red[j * 64 + tid];
        out[(bt * 64 + tid) * 1056 + 1024 + k] = s;
    }
}

extern "C" void kernel_launch(void* const* d_in, const int* in_sizes, int n_in,
                              void* d_out, int out_size, void* d_ws, size_t ws_size,
                              hipStream_t stream) {
    const float* x = (const float*)d_in[0];
    const float* W = (const float*)d_in[1];
    float* out = (float*)d_out;

    unsigned char* act2b = (unsigned char*)d_ws;    // 512 KB

    gemm_k<<<1024, 256, 0, stream>>>(x, W, act2b, out);
    pairfull_k<<<dim3(16, 32), 512, 0, stream>>>(act2b, out);
}